// Round 2
// baseline (80.139 us; speedup 1.0000x reference)
//
#include <hip/hip_runtime.h>
#include <hip/hip_bf16.h>

#define W_OUT 768
#define H_OUT 768
#define N_BOX 64
#define RECT_MAX 136  // max rect extent: bw<=256 -> 128 out px, +2 widen slack

// One block per box. Each block:
//  1) loads all 64 boxes to LDS, computes area_ok ballot
//  2) computes row_mask / col_mask for ITS OWN rectangle only (exact masks
//     over all 64 boxes, area_ok folded into col_mask)
//  3) scans its rectangle: pixel belongs exclusively to box n iff
//     row_mask[h] & col_mask[w] == (1ull<<n); takes max sigmoid(conf)
//  4) shuffle+LDS max reduce, writes out[n] (score) and out[64+n] (valid)
// No atomics, no workspace, single launch.
__global__ __launch_bounds__(256) void box_scores_kernel(
    const float* __restrict__ conf,
    const float* __restrict__ boxes,
    float* __restrict__ out) {
  const int n = blockIdx.x;
  const int tid = threadIdx.x;

  __shared__ float bx1[N_BOX], by1[N_BOX], bx2[N_BOX], by2[N_BOX];
  __shared__ unsigned long long area_sh;
  __shared__ unsigned long long rowm[RECT_MAX], colm[RECT_MAX];
  __shared__ float wmax[4];

  if (tid < N_BOX) {  // exactly wave 0
    const float x1 = boxes[tid * 5 + 0];
    const float y1 = boxes[tid * 5 + 1];
    const float x2 = boxes[tid * 5 + 2];
    const float y2 = boxes[tid * 5 + 3];
    bx1[tid] = x1; by1[tid] = y1; bx2[tid] = x2; by2[tid] = y2;
    const bool ok = ((x2 - x1) * (y2 - y1)) != 0.0f;
    const unsigned long long am = __ballot(ok);
    if (tid == 0) area_sh = am;
  }
  __syncthreads();

  // My rectangle in output-pixel coords. Conservative by 1 px each side
  // (floor/ceil widening) — the exact per-pixel mask check filters it.
  const float mx1 = bx1[n], my1 = by1[n], mx2 = bx2[n], my2 = by2[n];
  const int w0 = max(0, (int)floorf((mx1 - 1.0f) * 0.5f));
  const int w1 = min(W_OUT - 1, (int)ceilf((mx2 - 1.0f) * 0.5f));
  const int h0 = max(0, (int)floorf((my1 - 1.0f) * 0.5f));
  const int h1 = min(H_OUT - 1, (int)ceilf((my2 - 1.0f) * 0.5f));
  const int nw = w1 - w0 + 1;
  const int nh = h1 - h0 + 1;

  // Build masks for my rectangle (each <= 130 entries; 256 threads -> 1 pass).
  const unsigned long long area = area_sh;
  for (int r = tid; r < nh; r += 256) {
    const float c = (float)(h0 + r) * 2.0f + 1.0f;  // yc = STRIDE*h + STRIDE/2
    unsigned long long m = 0ull;
#pragma unroll
    for (int k = 0; k < N_BOX; ++k)
      if (c >= by1[k] && c <= by2[k]) m |= (1ull << k);
    rowm[r] = m;
  }
  for (int r = tid; r < nw; r += 256) {
    const float c = (float)(w0 + r) * 2.0f + 1.0f;
    unsigned long long m = 0ull;
#pragma unroll
    for (int k = 0; k < N_BOX; ++k)
      if (c >= bx1[k] && c <= bx2[k]) m |= (1ull << k);
    colm[r] = m & area;  // fold area_ok
  }
  __syncthreads();

  // Scan rectangle: lanes along x (coalesced conf reads), 4 row-streams.
  const unsigned long long mybit = 1ull << n;
  const int tx = tid & 63;
  const int ty = tid >> 6;
  float best = 0.0f;
  for (int r = ty; r < nh; r += 4) {
    const unsigned long long rm = rowm[r];
    const float* crow = conf + (h0 + r) * W_OUT + w0;
    for (int c = tx; c < nw; c += 64) {
      if ((rm & colm[c]) == mybit) {  // inside me AND count==1
        const float x = crow[c];
        best = fmaxf(best, 1.0f / (1.0f + __expf(-x)));  // sigmoid > 0 always
      }
    }
  }

  // Reduce: wave shuffle, then 4 waves via LDS.
#pragma unroll
  for (int off = 32; off; off >>= 1) best = fmaxf(best, __shfl_xor(best, off));
  if ((tid & 63) == 0) wmax[tid >> 6] = best;
  __syncthreads();
  if (tid == 0) {
    const float b = fmaxf(fmaxf(wmax[0], wmax[1]), fmaxf(wmax[2], wmax[3]));
    out[n] = b;                               // scores
    out[N_BOX + n] = (b > 0.0f) ? 1.0f : 0.0f;  // valid == mask.any()
  }
}

extern "C" void kernel_launch(void* const* d_in, const int* in_sizes, int n_in,
                              void* d_out, int out_size, void* d_ws, size_t ws_size,
                              hipStream_t stream) {
  const float* conf = (const float*)d_in[0];
  const float* bboxes = (const float*)d_in[2];  // [x1,y1,x2,y2,cls] x 64
  float* out = (float*)d_out;
  box_scores_kernel<<<N_BOX, 256, 0, stream>>>(conf, bboxes, out);
}